// Round 2
// baseline (283.192 us; speedup 1.0000x reference)
//
#include <hip/hip_runtime.h>
#include <hip/hip_bf16.h>

#define NTOK   16384   // b*l = 4*4096
#define DIM    2048
#define NGRP   8
#define HDG    256
#define NIN    512     // K*HDG

typedef float f32x4 __attribute__((ext_vector_type(4)));
typedef short bf16x8 __attribute__((ext_vector_type(8)));

static __device__ __forceinline__ unsigned short f2bf(float f) {
    unsigned int u = __builtin_bit_cast(unsigned int, f);
    u = (u + 0x7fffu + ((u >> 16) & 1u)) >> 16;   // round-to-nearest-even
    return (unsigned short)u;
}

// ---------------- Kernel A: WmT[n][k] = bf16(Wm[k][n]) ----------------
__global__ __launch_bounds__(256) void prep_wm(const float* __restrict__ Wm,
                                               ushort* __restrict__ WmT) {
    __shared__ float tile[64][65];
    const int bk = blockIdx.x * 64;
    const int bn = blockIdx.y * 64;
    const int t = threadIdx.x;
    const int r = t >> 4;           // 0..15
    const int c = (t & 15) * 4;     // 0..60
#pragma unroll
    for (int i = 0; i < 4; i++) {
        const float4 v = *(const float4*)&Wm[(bk + r + i * 16) * 512 + bn + c];
        tile[r + i * 16][c + 0] = v.x;
        tile[r + i * 16][c + 1] = v.y;
        tile[r + i * 16][c + 2] = v.z;
        tile[r + i * 16][c + 3] = v.w;
    }
    __syncthreads();
#pragma unroll
    for (int i = 0; i < 4; i++) {
        const int n = r + i * 16;
        ushort4 o;
        o.x = f2bf(tile[c + 0][n]);
        o.y = f2bf(tile[c + 1][n]);
        o.z = f2bf(tile[c + 2][n]);
        o.w = f2bf(tile[c + 3][n]);
        *(ushort4*)&WmT[(bn + n) * 512 + bk + c] = o;
    }
}

// ------- Kernel B: gate (f32) + softmax + top2 + gather + masked copy -------
// 256 threads = 4 waves, 8 tokens per block. ONE barrier per block.
__global__ __launch_bounds__(256) void gate_gather(
        const float* __restrict__ x, const float* __restrict__ Wg,
        float* __restrict__ out, ushort* __restrict__ hbuf,
        int* __restrict__ Isel) {
    const int t = threadIdx.x;
    const int lane = t & 63;
    const int wave = t >> 6;
    // Wg register-resident: wgr[j][g] = Wg[(t*8+j)*8 + g]
    float wgr[8][8];
#pragma unroll
    for (int j = 0; j < 8; j++) {
        const float4 a = *(const float4*)&Wg[(t * 8 + j) * 8];
        const float4 b = *(const float4*)&Wg[(t * 8 + j) * 8 + 4];
        wgr[j][0] = a.x; wgr[j][1] = a.y; wgr[j][2] = a.z; wgr[j][3] = a.w;
        wgr[j][4] = b.x; wgr[j][5] = b.y; wgr[j][6] = b.z; wgr[j][7] = b.w;
    }
    __shared__ float red[8][4][8];   // [token][wave][group]
    const int tok0 = blockIdx.x * 8;

    const bool b0 = lane & 1;
    const bool b1 = lane & 2;
    const bool b2 = lane & 4;

    // ---- Phase 1: per-wave logit partials for 8 tokens ----
#pragma unroll
    for (int tt = 0; tt < 8; tt++) {
        const int tok = tok0 + tt;
        const float4 x0 = *(const float4*)&x[tok * DIM + t * 8];
        const float4 x1 = *(const float4*)&x[tok * DIM + t * 8 + 4];
        const float xr[8] = {x0.x, x0.y, x0.z, x0.w, x1.x, x1.y, x1.z, x1.w};
        float acc[8];
#pragma unroll
        for (int g = 0; g < 8; g++) acc[g] = 0.f;
#pragma unroll
        for (int j = 0; j < 8; j++)
#pragma unroll
            for (int g = 0; g < 8; g++)
                acc[g] = fmaf(xr[j], wgr[j][g], acc[g]);
        // distributed reduce: lane l ends with full-wave sum of group (l&7)
        float n_[4];
#pragma unroll
        for (int j = 0; j < 4; j++) {
            const float keep = b0 ? acc[2 * j + 1] : acc[2 * j];
            const float send = b0 ? acc[2 * j] : acc[2 * j + 1];
            n_[j] = keep + __shfl_xor(send, 1, 64);
        }
        float m_[2];
#pragma unroll
        for (int j = 0; j < 2; j++) {
            const float keep = b1 ? n_[2 * j + 1] : n_[2 * j];
            const float send = b1 ? n_[2 * j] : n_[2 * j + 1];
            m_[j] = keep + __shfl_xor(send, 2, 64);
        }
        float v;
        {
            const float keep = b2 ? m_[1] : m_[0];
            const float send = b2 ? m_[0] : m_[1];
            v = keep + __shfl_xor(send, 4, 64);
        }
        v += __shfl_xor(v, 8, 64);
        v += __shfl_xor(v, 16, 64);
        v += __shfl_xor(v, 32, 64);
        if (lane < 8) red[tt][wave][lane] = v;
    }
    __syncthreads();

    // ---- Phase 2: each half-wave owns one token ----
    const int ll = lane & 31;
    const int tok_local = wave * 2 + (lane >> 5);
    const int tok = tok0 + tok_local;

    float v = red[tok_local][ll >> 3][ll & 7];
    v += __shfl_xor(v, 8, 64);
    v += __shfl_xor(v, 16, 64);
    // gather all 8 logits: c[j] = logit of group (ll&7)^j
    float c[8];
    c[0] = v;
    c[1] = __shfl_xor(c[0], 1, 64);
    c[2] = __shfl_xor(c[0], 2, 64);
    c[3] = __shfl_xor(c[1], 2, 64);
    c[4] = __shfl_xor(c[0], 4, 64);
    c[5] = __shfl_xor(c[1], 4, 64);
    c[6] = __shfl_xor(c[2], 4, 64);
    c[7] = __shfl_xor(c[3], 4, 64);
    const int gbase = ll & 7;

    float m = c[0];
#pragma unroll
    for (int j = 1; j < 8; j++) m = fmaxf(m, c[j]);
    float sum = 0.f;
#pragma unroll
    for (int j = 0; j < 8; j++) sum += __expf(c[j] - m);
    // top-2 with lowest-index tie-break (jax top_k semantics)
    int i0 = 8; float v0 = -3.4e38f;
#pragma unroll
    for (int j = 0; j < 8; j++) {
        const int g = gbase ^ j;
        if (c[j] > v0 || (c[j] == v0 && g < i0)) { v0 = c[j]; i0 = g; }
    }
    int i1 = 8; float v1 = -3.4e38f;
#pragma unroll
    for (int j = 0; j < 8; j++) {
        const int g = gbase ^ j;
        if (g != i0 && (c[j] > v1 || (c[j] == v1 && g < i1))) { v1 = c[j]; i1 = g; }
    }
    const float inv = 1.0f / sum;
    const float G0 = __expf(v0 - m) * inv;
    const float G1 = __expf(v1 - m) * inv;

    // masked copy: unselected groups -> out; selected -> scaled bf16 hbuf
#pragma unroll
    for (int cgrp = 0; cgrp < 8; cgrp++) {
        const float4 f0 = *(const float4*)&x[tok * DIM + cgrp * HDG + ll * 8];
        const float4 f1 = *(const float4*)&x[tok * DIM + cgrp * HDG + ll * 8 + 4];
        if (cgrp == i0 || cgrp == i1) {
            const float gv  = (cgrp == i0) ? G0 : G1;
            const int slot  = (cgrp == i0) ? 0 : 1;
            int4 pk;
            pk.x = (int)f2bf(gv * f0.x) | ((int)f2bf(gv * f0.y) << 16);
            pk.y = (int)f2bf(gv * f0.z) | ((int)f2bf(gv * f0.w) << 16);
            pk.z = (int)f2bf(gv * f1.x) | ((int)f2bf(gv * f1.y) << 16);
            pk.w = (int)f2bf(gv * f1.z) | ((int)f2bf(gv * f1.w) << 16);
            *(int4*)&hbuf[tok * NIN + slot * HDG + ll * 8] = pk;
        } else {
            *(float4*)&out[tok * DIM + cgrp * HDG + ll * 8]     = f0;
            *(float4*)&out[tok * DIM + cgrp * HDG + ll * 8 + 4] = f1;
        }
    }
    if (ll == 0) {
        int2 s2; s2.x = i0; s2.y = i1;
        *(int2*)&Isel[tok * 2] = s2;
    }
}

// ------- Kernel C: D[n][tok] = WmT x h^T, double-buffered, vector epilogue -------
// 128(n) x 128(tok) tile, 4 waves (2x2), each wave 64x64 = 4x4 frags of 16x16x32.
__global__ __launch_bounds__(256) void gemm_scatter(
        const ushort* __restrict__ h, const ushort* __restrict__ WmT,
        const float* __restrict__ bm, const int* __restrict__ Isel,
        float* __restrict__ out) {
    __shared__ ushort Hs[2][128][40];   // [buf][token][k], padded rows (80B)
    __shared__ ushort Ws[2][128][40];   // [buf][n][k]
    const int t = threadIdx.x;
    const int lane = t & 63;
    const int wave = t >> 6;
    const int wn = (wave >> 1) * 64;    // wave's n offset in tile
    const int wt = (wave & 1) * 64;     // wave's token offset in tile
    const int n_blk = blockIdx.x * 128;
    const int tok_blk = blockIdx.y * 128;

    const int sr = t >> 2;              // staging row 0..63
    const int sc = (t & 3) * 8;         // staging col chunk (bf16 units)

    const ushort* hp0 = &h[(tok_blk + sr) * 512 + sc];
    const ushort* hp1 = hp0 + 64 * 512;
    const ushort* wp0 = &WmT[(n_blk + sr) * 512 + sc];
    const ushort* wp1 = wp0 + 64 * 512;

    int4 rh0 = *(const int4*)hp0;
    int4 rh1 = *(const int4*)hp1;
    int4 rw0 = *(const int4*)wp0;
    int4 rw1 = *(const int4*)wp1;

    f32x4 acc[4][4];
#pragma unroll
    for (int i = 0; i < 4; i++)
#pragma unroll
        for (int j = 0; j < 4; j++)
            acc[i][j] = (f32x4){0.f, 0.f, 0.f, 0.f};

    const int fr = lane & 15;
    const int kh = (lane >> 4) * 8;

    for (int k = 0; k < 16; ++k) {
        const int b = k & 1;
        *(int4*)&Hs[b][sr][sc]      = rh0;
        *(int4*)&Hs[b][sr + 64][sc] = rh1;
        *(int4*)&Ws[b][sr][sc]      = rw0;
        *(int4*)&Ws[b][sr + 64][sc] = rw1;
        __syncthreads();
        if (k < 15) {
            const int off = (k + 1) * 32;
            rh0 = *(const int4*)(hp0 + off);
            rh1 = *(const int4*)(hp1 + off);
            rw0 = *(const int4*)(wp0 + off);
            rw1 = *(const int4*)(wp1 + off);
        }
        bf16x8 av[4], bv[4];
#pragma unroll
        for (int i = 0; i < 4; i++) av[i] = *(const bf16x8*)&Ws[b][wn + i * 16 + fr][kh];
#pragma unroll
        for (int j = 0; j < 4; j++) bv[j] = *(const bf16x8*)&Hs[b][wt + j * 16 + fr][kh];
#pragma unroll
        for (int i = 0; i < 4; i++)
#pragma unroll
            for (int j = 0; j < 4; j++)
                acc[i][j] = __builtin_amdgcn_mfma_f32_16x16x32_bf16(
                    av[i], bv[j], acc[i][j], 0, 0, 0);
        // one barrier per iter is enough with double buffering: next iter's
        // ds_writes target buf b^1, whose last readers were separated by this
        // iteration's barrier.
    }

    // epilogue: D row = n (lane>>4)*4+r, D col = token (lane&15)
    const int rq = (lane >> 4) * 4;
    const int n_base = n_blk + wn;          // wave-uniform
    const int s = n_base >> 8;              // which of the 2 selected slots
    const int n_off_base = (n_base & 255) + rq;
    float4 bmv[4];
#pragma unroll
    for (int i = 0; i < 4; i++) bmv[i] = *(const float4*)&bm[n_base + i * 16 + rq];
#pragma unroll
    for (int j = 0; j < 4; j++) {
        const int tok = tok_blk + wt + j * 16 + fr;
        const int2 sel = *(const int2*)&Isel[tok * 2];
        const int grp = s ? sel.y : sel.x;
        float* op = &out[tok * DIM + grp * HDG + n_off_base];
#pragma unroll
        for (int i = 0; i < 4; i++) {
            float4 o;
            o.x = acc[i][j][0] + bmv[i].x;
            o.y = acc[i][j][1] + bmv[i].y;
            o.z = acc[i][j][2] + bmv[i].z;
            o.w = acc[i][j][3] + bmv[i].w;
            *(float4*)&op[i * 16] = o;
        }
    }
}

extern "C" void kernel_launch(void* const* d_in, const int* in_sizes, int n_in,
                              void* d_out, int out_size, void* d_ws, size_t ws_size,
                              hipStream_t stream) {
    const float* x  = (const float*)d_in[0];
    const float* Wg = (const float*)d_in[1];
    const float* Wm = (const float*)d_in[2];
    const float* bm = (const float*)d_in[3];
    float* out = (float*)d_out;

    char* ws = (char*)d_ws;
    ushort* hbuf = (ushort*)ws;                                   // 16 MiB
    ushort* WmT  = (ushort*)(ws + (size_t)16 * 1024 * 1024);      // 512 KiB
    int*    Isel = (int*)(ws + (size_t)16 * 1024 * 1024 + 512 * 1024);

    prep_wm<<<dim3(8, 8), 256, 0, stream>>>(Wm, WmT);
    gate_gather<<<NTOK / 8, 256, 0, stream>>>(x, Wg, out, hbuf, Isel);
    gemm_scatter<<<dim3(NIN / 128, NTOK / 128), 256, 0, stream>>>(hbuf, WmT, bm, Isel, out);
}